// Round 5
// baseline (902.895 us; speedup 1.0000x reference)
//
#include <hip/hip_runtime.h>
#include <stdint.h>
#include <math.h>

// ---------------------------------------------------------------------------
// PAAE layer, MI355X (gfx950). Round 5: software-pipelined 256x256 GEMM.
//  k_gemm256p: per phase (k-half=32), ds_reads for half g+1 issue BEFORE the
//  MFMA cluster for half g (double-buffered operand regs, static P/Q names).
//  Compiler scoreboard emits lgkmcnt(12) before MFMA -> LDS port drains next
//  phase's reads under the MFMA cluster. Ring-4 k-half slots; stage(g+3)
//  issued AFTER the phase barrier (slot-free proof: all waves' reads of half
//  g-1 were lgkm-drained before their MFMA(g-1), which precedes this barrier).
//  vmcnt(4) steady (2-phase lookahead ~2600cyc > 900cyc HBM latency).
//  16x16x32 MFMA + (rl>>1)&3 chunk-XOR swizzle (R3-verified, 0 conflicts).
// ---------------------------------------------------------------------------

typedef short short8 __attribute__((ext_vector_type(8)));
typedef unsigned short ushort8 __attribute__((ext_vector_type(8)));
typedef float f32x4 __attribute__((ext_vector_type(4)));

#define DEVI static __device__ __forceinline__

DEVI unsigned short f2bf(float f) {  // RNE float -> bf16 bits
  uint32_t u = __builtin_bit_cast(uint32_t, f);
  return (unsigned short)((u + 0x7fffu + ((u >> 16) & 1u)) >> 16);
}
DEVI float sigmoidf_(float x) { return 1.0f / (1.0f + expf(-x)); }

DEVI void gld16(const void* g, void* l) {
  __builtin_amdgcn_global_load_lds(
      (const __attribute__((address_space(1))) unsigned int*)g,
      (__attribute__((address_space(3))) unsigned int*)l, 16, 0, 0);
}

// ---------------------------------------------------------------------------
__global__ __launch_bounds__(256) void k_f32_to_bf16(
    const float* __restrict__ s, unsigned short* __restrict__ d, long n) {
  long i0 = ((long)blockIdx.x * 256 + threadIdx.x) * 8;
  long stride = (long)gridDim.x * 256 * 8;
  for (long i = i0; i < n; i += stride) {
    f32x4 a = *(const f32x4*)(s + i);
    f32x4 b = *(const f32x4*)(s + i + 4);
    ushort8 o;
    o[0] = f2bf(a[0]); o[1] = f2bf(a[1]); o[2] = f2bf(a[2]); o[3] = f2bf(a[3]);
    o[4] = f2bf(b[0]); o[5] = f2bf(b[1]); o[6] = f2bf(b[2]); o[7] = f2bf(b[3]);
    *(ushort8*)(d + i) = o;
  }
}

// ---------------------------------------------------------------------------
// Pipelined 256x256 bf16 GEMM: C[M,N] = A[M,K] * B[N,K]^T.
// EPI 0: outF[z*zsf + row*N + col] = acc   (split-K partial)
// EPI 1: outB = bf16(tanh(acc + bias[row]))
// Requires kchunk%64==0 (NPH even), kchunk>=128.
// ---------------------------------------------------------------------------
template <int EPI>
__global__ __launch_bounds__(512, 2) void k_gemm256p(
    const unsigned short* __restrict__ A, const unsigned short* __restrict__ B,
    float* __restrict__ outF, unsigned short* __restrict__ outB,
    const float* __restrict__ bias, int M, int N, int K, int kchunk,
    long zsf) {
  __shared__ unsigned short lds[65536];  // A slots [4][256][32] @0; B @32768
  const int tid = threadIdx.x, lane = tid & 63;
  const int wid = tid >> 6, wr = wid >> 2, wc = wid & 3;
  const int bm = blockIdx.x * 256, bn = blockIdx.y * 256;
  const int kz = blockIdx.z;
  const long kbase = (long)kz * kchunk;
  const int NPH = kchunk >> 5;  // even

  const int R0 = tid >> 2, Q = tid & 3;       // staging row / 16B chunk
  const int qd = Q ^ ((R0 >> 1) & 3);         // inverse-swizzled source chunk
  const int q = lane >> 4, rl = lane & 15;    // frag k-quarter / row-in-frag
  const int qe = (q ^ ((rl >> 1) & 3)) << 3;  // swizzled read offset (shorts)

  f32x4 acc[8][4] = {};

  // per-lane global sources (row part fixed, k varies per stage batch)
  const unsigned short* ga0 = A + (size_t)(bm + R0) * K + kbase + qd * 8;
  const unsigned short* ga1 = A + (size_t)(bm + 128 + R0) * K + kbase + qd * 8;
  const unsigned short* gb0 = B + (size_t)(bn + R0) * K + kbase + qd * 8;
  const unsigned short* gb1 = B + (size_t)(bn + 128 + R0) * K + kbase + qd * 8;
  const int ldst = R0 * 32 + Q * 8;  // dest offset within slot (shorts)

  auto stage = [&](int j) {  // one batch = 4 gld16
    const int sb = (j & 3) * 8192;
    const long kk = (long)j << 5;
    gld16(ga0 + kk, &lds[sb + ldst]);
    gld16(ga1 + kk, &lds[sb + 4096 + ldst]);
    gld16(gb0 + kk, &lds[32768 + sb + ldst]);
    gld16(gb1 + kk, &lds[32768 + sb + 4096 + ldst]);
  };

  // constant fragment read offsets (shorts within slot)
  int offA[8], offB[4];
#pragma unroll
  for (int m = 0; m < 8; m++) offA[m] = (wr * 128 + m * 16 + rl) * 32 + qe;
#pragma unroll
  for (int n = 0; n < 4; n++) offB[n] = (wc * 64 + n * 16 + rl) * 32 + qe;

  auto readh = [&](int g, short8* av, short8* bv) {
    const int sb = (g & 3) * 8192;
#pragma unroll
    for (int m = 0; m < 8; m++) av[m] = *(const short8*)(lds + sb + offA[m]);
#pragma unroll
    for (int n = 0; n < 4; n++)
      bv[n] = *(const short8*)(lds + 32768 + sb + offB[n]);
  };

  auto domfma = [&](short8* av, short8* bv) {
    __builtin_amdgcn_s_setprio(1);
#pragma unroll
    for (int m = 0; m < 8; m++)
#pragma unroll
      for (int n = 0; n < 4; n++)
        acc[m][n] = __builtin_amdgcn_mfma_f32_16x16x32_bf16(av[m], bv[n],
                                                            acc[m][n], 0, 0, 0);
    __builtin_amdgcn_s_setprio(0);
  };

  // vmbar(g): before reading half g+1. Drains batch g+1; batches issued so
  // far reach only g+2, so steady vmcnt(4), tail vmcnt(0).
  auto vmbar = [&](int g) {
    if (g + 2 < NPH)
      asm volatile("s_waitcnt vmcnt(4)\n\ts_barrier" ::: "memory");
    else
      asm volatile("s_waitcnt vmcnt(0)\n\ts_barrier" ::: "memory");
  };

  short8 aP[8], bP[4], aQ[8], bQ[4];

  stage(0); stage(1); stage(2);
  asm volatile("s_waitcnt vmcnt(8)\n\ts_barrier" ::: "memory");
  readh(0, aP, bP);

  for (int g = 0; g < NPH; g += 2) {
    // ---- half g (operands in P), prefetch half g+1 into Q ----
    vmbar(g);                         // slot g+1 ready; slot g-1 free
    if (g + 3 < NPH) stage(g + 3);    // into slot (g-1)&3
    readh(g + 1, aQ, bQ);             // g+1 <= NPH-1 always
    __builtin_amdgcn_sched_barrier(0);
    domfma(aP, bP);
    // ---- half g+1 (operands in Q), prefetch half g+2 into P ----
    if (g + 2 < NPH) {
      vmbar(g + 1);
      if (g + 4 < NPH) stage(g + 4);
      readh(g + 2, aP, bP);
    }
    __builtin_amdgcn_sched_barrier(0);
    domfma(aQ, bQ);
  }

#pragma unroll
  for (int m = 0; m < 8; m++) {
#pragma unroll
    for (int n = 0; n < 4; n++) {
      const int col = bn + wc * 64 + n * 16 + rl;
#pragma unroll
      for (int r = 0; r < 4; r++) {
        const int row = bm + wr * 128 + m * 16 + q * 4 + r;
        const float v = acc[m][n][r];
        if (EPI == 0)
          outF[(long)kz * zsf + (size_t)row * N + col] = v;
        else
          outB[(size_t)row * N + col] = f2bf(tanhf(v + bias[row]));
      }
    }
  }
}

// ---------------------------------------------------------------------------
// 128x128 bf16 GEMM (for h, K=64), swizzled.
// EPI 2: outB = bf16(tanh(relu(acc + bias[col])))
// ---------------------------------------------------------------------------
template <int EPI>
__global__ __launch_bounds__(256) void k_gemm128(
    const unsigned short* __restrict__ A, const unsigned short* __restrict__ B,
    float* __restrict__ outF, unsigned short* __restrict__ outB,
    const float* __restrict__ bias, int M, int N, int K) {
  __shared__ unsigned short As[128 * 32];
  __shared__ unsigned short Bs[128 * 32];
  const int tid = threadIdx.x, lane = tid & 63, wid = tid >> 6;
  const int wr = wid >> 1, wc = wid & 1;
  const int bm = blockIdx.x * 128, bn = blockIdx.y * 128;
  const int c0 = tid, c1 = tid + 256;
  const int s0 = ((c0 & 3) ^ ((c0 >> 3) & 3)) << 3;
  const int s1 = ((c1 & 3) ^ ((c1 >> 3) & 3)) << 3;
  const int rl = lane & 15, q = lane >> 4;
  const int qe = (q ^ ((rl >> 1) & 3)) << 3;

  f32x4 acc[4][4] = {};

  for (int k0 = 0; k0 < K; k0 += 32) {
    gld16(A + (size_t)(bm + (c0 >> 2)) * K + k0 + s0, As + c0 * 8);
    gld16(A + (size_t)(bm + (c1 >> 2)) * K + k0 + s1, As + c1 * 8);
    gld16(B + (size_t)(bn + (c0 >> 2)) * K + k0 + s0, Bs + c0 * 8);
    gld16(B + (size_t)(bn + (c1 >> 2)) * K + k0 + s1, Bs + c1 * 8);
    __syncthreads();

    short8 af[4], bfr[4];
#pragma unroll
    for (int mi = 0; mi < 4; mi++)
      af[mi] = *(const short8*)(As + (wr * 64 + mi * 16 + rl) * 32 + qe);
#pragma unroll
    for (int ni = 0; ni < 4; ni++)
      bfr[ni] = *(const short8*)(Bs + (wc * 64 + ni * 16 + rl) * 32 + qe);
#pragma unroll
    for (int mi = 0; mi < 4; mi++)
#pragma unroll
      for (int ni = 0; ni < 4; ni++)
        acc[mi][ni] = __builtin_amdgcn_mfma_f32_16x16x32_bf16(
            af[mi], bfr[ni], acc[mi][ni], 0, 0, 0);
    __syncthreads();
  }

#pragma unroll
  for (int mi = 0; mi < 4; mi++) {
#pragma unroll
    for (int ni = 0; ni < 4; ni++) {
      const int col = bn + wc * 64 + ni * 16 + rl;
#pragma unroll
      for (int r = 0; r < 4; r++) {
        const int row = bm + wr * 64 + mi * 16 + q * 4 + r;
        const float v = acc[mi][ni][r];
        if (EPI == 0) {
          outF[(size_t)row * N + col] = v;
        } else if (EPI == 1) {
          outB[(size_t)row * N + col] = f2bf(tanhf(v + bias[row]));
        } else {
          outB[(size_t)row * N + col] = f2bf(tanhf(fmaxf(v + bias[col], 0.0f)));
        }
      }
    }
  }
}

// ---------------------------------------------------------------------------
// Skinny GEMM, N=64, split-K. grid: (M/64, KS, nbr)
// ---------------------------------------------------------------------------
template <int AMODE, int BMODE>
__global__ __launch_bounds__(256) void k_sgemm64s(
    const void* __restrict__ A0, const void* __restrict__ A1,
    const void* __restrict__ B0, const void* __restrict__ B1,
    float* __restrict__ P, int kchunk, int lda, int ldb, int M) {
  const int br = blockIdx.z, kz = blockIdx.y, KS = gridDim.y;
  const void* Av = br ? A1 : A0;
  const void* Bv = br ? B1 : B0;

  __shared__ unsigned short As[64 * 40];
  __shared__ unsigned short Bs[64 * 40];
  const int tid = threadIdx.x, lane = tid & 63, w = tid >> 6;
  const int tm = blockIdx.x * 64;

  f32x4 acc[4] = {};
  const int kbeg = kz * kchunk, kend = kbeg + kchunk;

  for (int k0 = kbeg; k0 < kend; k0 += 32) {
    if (AMODE == 0) {
      const float* Af = (const float*)Av;
      const int m = tid >> 2, k8 = (tid & 3) << 3;
      f32x4 x0 = *(const f32x4*)(Af + (size_t)(tm + m) * lda + k0 + k8);
      f32x4 x1 = *(const f32x4*)(Af + (size_t)(tm + m) * lda + k0 + k8 + 4);
      ushort8 o;
      o[0] = f2bf(x0[0]); o[1] = f2bf(x0[1]); o[2] = f2bf(x0[2]); o[3] = f2bf(x0[3]);
      o[4] = f2bf(x1[0]); o[5] = f2bf(x1[1]); o[6] = f2bf(x1[2]); o[7] = f2bf(x1[3]);
      *(ushort8*)(As + m * 40 + k8) = o;
    } else if (AMODE == 1) {
      const float* Af = (const float*)Av;
#pragma unroll
      for (int t = 0; t < 2; t++) {
        const int c = tid + t * 256;
        const int u = c >> 4, i4 = (c & 15) << 2;
        f32x4 x = *(const f32x4*)(Af + (size_t)(k0 + u) * lda + tm + i4);
        As[(i4 + 0) * 40 + u] = f2bf(x[0]);
        As[(i4 + 1) * 40 + u] = f2bf(x[1]);
        As[(i4 + 2) * 40 + u] = f2bf(x[2]);
        As[(i4 + 3) * 40 + u] = f2bf(x[3]);
      }
    } else {
      const unsigned short* Ab = (const unsigned short*)Av;
      const int m = tid >> 2, k8 = (tid & 3) << 3;
      *(ushort8*)(As + m * 40 + k8) =
          *(const ushort8*)(Ab + (size_t)(tm + m) * lda + k0 + k8);
    }
    if (BMODE == 0) {
      const float* Bf = (const float*)Bv;
      const int n = tid >> 2, k8 = (tid & 3) << 3;
      f32x4 x0 = *(const f32x4*)(Bf + (size_t)n * ldb + k0 + k8);
      f32x4 x1 = *(const f32x4*)(Bf + (size_t)n * ldb + k0 + k8 + 4);
      ushort8 o;
      o[0] = f2bf(x0[0]); o[1] = f2bf(x0[1]); o[2] = f2bf(x0[2]); o[3] = f2bf(x0[3]);
      o[4] = f2bf(x1[0]); o[5] = f2bf(x1[1]); o[6] = f2bf(x1[2]); o[7] = f2bf(x1[3]);
      *(ushort8*)(Bs + n * 40 + k8) = o;
    } else {
      const unsigned short* Bb = (const unsigned short*)Bv;
      const int n = tid >> 2, k8 = (tid & 3) << 3;
      *(ushort8*)(Bs + n * 40 + k8) =
          *(const ushort8*)(Bb + (size_t)n * ldb + k0 + k8);
    }
    __syncthreads();

    const int kr = (lane >> 4) << 3;
    short8 a = *(const short8*)(As + (w * 16 + (lane & 15)) * 40 + kr);
#pragma unroll
    for (int ni = 0; ni < 4; ni++) {
      short8 bb = *(const short8*)(Bs + (ni * 16 + (lane & 15)) * 40 + kr);
      acc[ni] = __builtin_amdgcn_mfma_f32_16x16x32_bf16(a, bb, acc[ni], 0, 0, 0);
    }
    __syncthreads();
  }

  float* out = P + ((size_t)(br * KS + kz) * M) * 64;
#pragma unroll
  for (int ni = 0; ni < 4; ni++) {
    const int col = ni * 16 + (lane & 15);
#pragma unroll
    for (int r = 0; r < 4; r++) {
      const int row = tm + w * 16 + ((lane >> 4) << 2) + r;
      out[(size_t)row * 64 + col] = acc[ni][r];
    }
  }
}

// ---------------------------------------------------------------------------
template <int WF, int WB, int WT>
__global__ __launch_bounds__(256) void k_reduce(
    const float* __restrict__ P, size_t pbr_stride, float* F0, float* F1,
    unsigned short* Bo0, unsigned short* Bo1, unsigned short* T0,
    unsigned short* T1, int M, int KS, int ldT) {
  const int br = blockIdx.y;
  const float* Pp = P + (size_t)br * pbr_stride;
  const size_t i = (size_t)blockIdx.x * 256 + threadIdx.x;
  const size_t n = (size_t)M * 64;
  float s = 0.f;
  for (int k = 0; k < KS; k++) s += Pp[(size_t)k * n + i];
  if (WF) (br ? F1 : F0)[i] = s;
  if (WB) (br ? Bo1 : Bo0)[i] = f2bf(s);
  if (WT) {
    const int row = (int)(i >> 6), col = (int)(i & 63);
    (br ? T1 : T0)[(size_t)col * ldT + row] = f2bf(s);
  }
}

// ---------------------------------------------------------------------------
__global__ __launch_bounds__(256) void k_softmax(
    const float* __restrict__ S0, const float* __restrict__ S1,
    unsigned short* __restrict__ Pout) {
  const int row = blockIdx.x, tid = threadIdx.x;
  const float* s0 = S0 + (size_t)row * 4096;
  const float* s1 = S1 + (size_t)row * 4096;
  float v[16];
  float m = -1e30f;
#pragma unroll
  for (int j = 0; j < 16; j++) {
    v[j] = s0[tid + j * 256] + s1[tid + j * 256];
    m = fmaxf(m, v[j]);
  }
  __shared__ float red[4], red2[4];
  for (int o = 32; o; o >>= 1) m = fmaxf(m, __shfl_down(m, o));
  if ((tid & 63) == 0) red[tid >> 6] = m;
  __syncthreads();
  m = fmaxf(fmaxf(red[0], red[1]), fmaxf(red[2], red[3]));
  float sum = 0.0f;
#pragma unroll
  for (int j = 0; j < 16; j++) {
    v[j] = expf(v[j] - m);
    sum += v[j];
  }
  for (int o = 32; o; o >>= 1) sum += __shfl_down(sum, o);
  if ((tid & 63) == 0) red2[tid >> 6] = sum;
  __syncthreads();
  const float inv = 1.0f / (red2[0] + red2[1] + red2[2] + red2[3]);
  unsigned short* p = Pout + (size_t)row * 4096;
#pragma unroll
  for (int j = 0; j < 16; j++) p[tid + j * 256] = f2bf(v[j] * inv);
}

// ---------------------------------------------------------------------------
__global__ __launch_bounds__(256) void k_user(
    const float* __restrict__ ue_mp, const float* __restrict__ ueat_mp,
    const float* __restrict__ ue_pmp, const float* __restrict__ ueat_pmp,
    const float* __restrict__ mlp_w, const float* __restrict__ mlp_b,
    const float* __restrict__ tr_w, const float* __restrict__ tr_b,
    float* __restrict__ out) {
  const int tid = threadIdx.x, d = tid & 63, w = tid >> 6;
  const int m = blockIdx.x * 4 + w;
  __shared__ float fus[4][64];
  float a1 = mlp_b[d], a2 = a1;
  const float* r1 = ue_mp + (size_t)m * 64;
  const float* r2 = ueat_mp + (size_t)m * 64;
  const float* r3 = ue_pmp + (size_t)m * 64;
  const float* r4 = ueat_pmp + (size_t)m * 64;
  const float* w1 = mlp_w + (size_t)d * 128;
#pragma unroll 8
  for (int k = 0; k < 64; k++) {
    const float wv = w1[k];
    a1 += r1[k] * wv;
    a2 += r3[k] * wv;
  }
#pragma unroll 8
  for (int k = 0; k < 64; k++) {
    const float wv = w1[64 + k];
    a1 += r2[k] * wv;
    a2 += r4[k] * wv;
  }
  const float u1 = sigmoidf_(a1), u2 = sigmoidf_(a2);
  const float rate = sigmoidf_(u1 + u2);
  fus[w][d] = rate * u1 + (1.0f - rate) * u2;
  __syncthreads();
  float o = tr_b[d];
  const float* tw = tr_w + (size_t)d * 64;
#pragma unroll 8
  for (int k = 0; k < 64; k++) o += fus[w][k] * tw[k];
  out[(size_t)m * 64 + d] = tanhf(o);
}

__global__ __launch_bounds__(256) void k_item(
    const float* __restrict__ ie_mp, const float* __restrict__ ie_pmp,
    const float* __restrict__ mlp_w, const float* __restrict__ mlp_b,
    float* __restrict__ out) {
  const int tid = threadIdx.x, d = tid & 63, w = tid >> 6;
  const int i = blockIdx.x * 4 + w;
  float a = mlp_b[d];
  const float* r1 = ie_mp + (size_t)i * 64;
  const float* r2 = ie_pmp + (size_t)i * 64;
  const float* wp = mlp_w + (size_t)d * 128;
#pragma unroll 8
  for (int k = 0; k < 64; k++) {
    a += r1[k] * wp[k];
    a += r2[k] * wp[64 + k];
  }
  out[(size_t)i * 64 + d] = sigmoidf_(a);
}

// ---------------------------------------------------------------------------
extern "C" void kernel_launch(void* const* d_in, const int* in_sizes, int n_in,
                              void* d_out, int out_size, void* d_ws,
                              size_t ws_size, hipStream_t stream) {
  const int U = 2048, I = 4096, D = 64, UI = 6144;

  const float* ui[2] = {(const float*)d_in[0], (const float*)d_in[1]};
  const float* Wu[2] = {(const float*)d_in[2], (const float*)d_in[3]};
  const float* Wi[2] = {(const float*)d_in[4], (const float*)d_in[5]};
  const float* mw[2] = {(const float*)d_in[6], (const float*)d_in[11]};
  const float* mb[2] = {(const float*)d_in[7], (const float*)d_in[12]};
  const float* aw[2] = {(const float*)d_in[8], (const float*)d_in[13]};
  const float* ab[2] = {(const float*)d_in[9], (const float*)d_in[14]};
  const float* Wat[2] = {(const float*)d_in[10], (const float*)d_in[15]};
  const float* mlp_w = (const float*)d_in[16];
  const float* mlp_b = (const float*)d_in[17];
  const float* tr_w = (const float*)d_in[18];
  const float* tr_b = (const float*)d_in[19];

  char* ws = (char*)d_ws;
  size_t off = 0;
  auto alloc = [&](size_t bytes) {
    void* p = ws + off;
    off += (bytes + 255) & ~(size_t)255;
    return p;
  };
  unsigned short* aw_bf = (unsigned short*)alloc((size_t)I * I * 2);
  unsigned short* Wat_bf = (unsigned short*)alloc((size_t)U * UI * 2);
  unsigned short* mw_bf = (unsigned short*)alloc((size_t)I * D * 2);
  unsigned short* h_bf = (unsigned short*)alloc((size_t)UI * I * 2);   // 48MB
  unsigned short* aT_bf = (unsigned short*)alloc((size_t)I * UI * 2);  // 48MB
  float* scores = (float*)alloc((size_t)U * I * 4);                    // 32MB
  unsigned short* at_bf = (unsigned short*)alloc((size_t)U * I * 2);
  unsigned short* x_bf[2];
  float* ue_f[2];
  float* ie_f[2];
  unsigned short* ieT[2];
  float* ueat_f[2];
  for (int b = 0; b < 2; b++) {
    x_bf[b] = (unsigned short*)alloc((size_t)UI * D * 2);
    ue_f[b] = (float*)alloc((size_t)U * D * 4);
    ie_f[b] = (float*)alloc((size_t)I * D * 4);
    ieT[b] = (unsigned short*)alloc((size_t)D * I * 2);
    ueat_f[b] = (float*)alloc((size_t)U * D * 4);
  }
  // Lifetime-based aliases:
  float* pue = (float*)h_bf;       // dead before h written
  float* pie = (float*)aT_bf;      // dead before aT written
  float* pueat = scores;           // clobbers scores AFTER softmax read them
  float* scores2 = (float*)h_bf;   // z=1 slab; h dead once aT is built
  const long zsf = (long)(scores2 - scores);

  const dim3 blk(256);

  // ue: [U,64] over K=I, both branches, KS=8
  k_sgemm64s<0, 0><<<dim3(U / 64, 8, 2), blk, 0, stream>>>(
      ui[0], ui[1], Wu[0], Wu[1], pue, I / 8, I, I, U);
  k_reduce<1, 1, 0><<<dim3(U * 64 / 256, 2), blk, 0, stream>>>(
      pue, (size_t)8 * U * 64, ue_f[0], ue_f[1], x_bf[0], x_bf[1], nullptr,
      nullptr, U, 8, 0);
  // ie: [I,64] over K=U (A = ui^T), both branches, KS=8
  k_sgemm64s<1, 0><<<dim3(I / 64, 8, 2), blk, 0, stream>>>(
      ui[0], ui[1], Wi[0], Wi[1], pie, U / 8, I, U, I);
  k_reduce<1, 1, 1><<<dim3(I * 64 / 256, 2), blk, 0, stream>>>(
      pie, (size_t)8 * I * 64, ie_f[0], ie_f[1], x_bf[0] + (size_t)U * D,
      x_bf[1] + (size_t)U * D, ieT[0], ieT[1], I, 8, I);

  for (int b = 0; b < 2; b++) {
    k_f32_to_bf16<<<2048, blk, 0, stream>>>(aw[b], aw_bf, (long)I * I);
    k_f32_to_bf16<<<2048, blk, 0, stream>>>(Wat[b], Wat_bf, (long)U * UI);
    k_f32_to_bf16<<<128, blk, 0, stream>>>(mw[b], mw_bf, (long)I * D);

    // h = tanh(relu(x @ mw^T + mb)) : [6144,4096], K=64
    k_gemm128<2><<<dim3(UI / 128, I / 128), blk, 0, stream>>>(
        x_bf[b], mw_bf, nullptr, h_bf, mb[b], UI, I, D);
    // aT = tanh(aw @ h^T + ab) : [4096,6144], K=4096
    k_gemm256p<1><<<dim3(I / 256, UI / 256, 1), dim3(512), 0, stream>>>(
        aw_bf, h_bf, nullptr, aT_bf, ab[b], I, UI, I, I, 0);
    // scores = Wat @ a : [2048,4096], K=6144, split-K z=2 ; grid 256
    k_gemm256p<0><<<dim3(U / 256, I / 256, 2), dim3(512), 0, stream>>>(
        Wat_bf, aT_bf, scores, nullptr, nullptr, U, I, UI, UI / 2, zsf);
    // softmax over slab0+slab1
    k_softmax<<<U, blk, 0, stream>>>(scores, scores2, at_bf);
    // ue_at = at @ ie : [U,64] over K=I, KS=8 (per branch)
    k_sgemm64s<2, 2><<<dim3(U / 64, 8, 1), blk, 0, stream>>>(
        at_bf, at_bf, ieT[b], ieT[b], pueat, I / 8, I, I, U);
    k_reduce<1, 0, 0><<<dim3(U * 64 / 256, 1), blk, 0, stream>>>(
        pueat, 0, ueat_f[b], ueat_f[b], nullptr, nullptr, nullptr, nullptr, U,
        8, 0);
  }

  float* out_user = (float*)d_out;
  float* out_item = (float*)d_out + (size_t)U * D;
  k_user<<<U / 4, blk, 0, stream>>>(ue_f[0], ueat_f[0], ue_f[1], ueat_f[1],
                                    mlp_w, mlp_b, tr_w, tr_b, out_user);
  k_item<<<I / 4, blk, 0, stream>>>(ie_f[0], ie_f[1], mlp_w, mlp_b, out_item);
}